// Round 3
// baseline (68.020 us; speedup 1.0000x reference)
//
#include <hip/hip_runtime.h>

#define NROW 128
#define NZ   8128      // 128*127/2
#define EPSF 1e-12f

// 16 lanes per row (4 rows per wave), 8 contiguous elements per lane.
// Closed form: 1 - s_j = prod_{k<j} (1 - z_k^2)  (telescoped scan recurrence)
//   L[i,j] = z[i,j]*sqrt(max(P_j,EPS)) (j<i), L[i,i]=sqrt(max(P_i,EPS)), 0 above.
// Lane-local products (7 muls) + 4-step segmented shuffle scan over 16 lanes.
__global__ __launch_bounds__(256) void chol_from_z_kernel(
    const float* __restrict__ z, float* __restrict__ out, int nrows_total)
{
    const int tid = blockIdx.x * blockDim.x + threadIdx.x;
    const int row = tid >> 4;            // 16 lanes per row
    const int l   = threadIdx.x & 15;    // lane within row segment
    if (row >= nrows_total) return;

    const int b = row >> 7;              // batch
    const int i = row & 127;             // row within batch

    const float* __restrict__ zr = z + (size_t)b * NZ + (size_t)((i * (i - 1)) >> 1);
    const int base = l * 8;              // first element position for this lane

    // Predicated loads: z=0 for p>=i  =>  factor (1-z^2)=1 automatically,
    // and avoids the 4B past-end read at (b=B-1, i=127).
    float zt[8];
    #pragma unroll
    for (int t = 0; t < 8; ++t) {
        const int p = base + t;
        zt[t] = (p < i) ? zr[p] : 0.0f;
    }

    // Lane-local inclusive products of factors f = 1 - z^2
    float c[8];
    float run = 1.0f;
    #pragma unroll
    for (int t = 0; t < 8; ++t) {
        run *= fmaf(-zt[t], zt[t], 1.0f);
        c[t] = run;
    }

    // Inclusive multiplicative scan of lane totals across the 16-lane segment
    float g = run;
    #pragma unroll
    for (int off = 1; off < 16; off <<= 1) {
        const float t = __shfl_up(g, off, 16);
        if (l >= off) g *= t;
    }
    // Exclusive prefix for this lane's block
    float e = __shfl_up(g, 1, 16);
    if (l == 0) e = 1.0f;

    // Per-element outputs
    float o[8];
    #pragma unroll
    for (int t = 0; t < 8; ++t) {
        const float pre = (t == 0) ? e : e * c[t - 1];   // exclusive prefix product
        const float sq  = sqrtf(fmaxf(pre, EPSF));
        const int   p   = base + t;
        o[t] = (p == i) ? sq : zt[t] * sq;               // zt=0 for p>i -> 0
    }

    float* __restrict__ orow = out + (size_t)row * NROW + base;  // 32B-aligned
    *reinterpret_cast<float4*>(orow)     = make_float4(o[0], o[1], o[2], o[3]);
    *reinterpret_cast<float4*>(orow + 4) = make_float4(o[4], o[5], o[6], o[7]);
}

extern "C" void kernel_launch(void* const* d_in, const int* in_sizes, int n_in,
                              void* d_out, int out_size, void* d_ws, size_t ws_size,
                              hipStream_t stream)
{
    const float* z = (const float*)d_in[0];
    float* out = (float*)d_out;

    const int B = in_sizes[0] / NZ;            // 2048
    const int nrows_total = B * NROW;          // 262144

    const int block = 256;                     // 4 waves = 16 rows per block
    const long long threads = (long long)nrows_total * 16;
    const int grid = (int)((threads + block - 1) / block);   // 16384
    chol_from_z_kernel<<<grid, block, 0, stream>>>(z, out, nrows_total);
}

// Round 4
// 40.835 us; speedup vs baseline: 1.6657x; 1.6657x over previous
//
#include <hip/hip_runtime.h>

#define NROW 128
#define NZ   8128      // 128*127/2
#define EPSF 1e-12f

// One WAVE per (batch,row); lane l owns adjacent elements {2l, 2l+1}.
// Closed form: 1 - s_j = prod_{k<j} (1 - z_k^2)   (telescoped recurrence)
//   L[i,j] = z[i,j]*sqrt(max(P_j,EPS)) (j<i), L[i,i]=sqrt(max(P_i,EPS)), 0 above.
// 64-lane multiplicative scan in 12 full-rate VALU ops via DPP
// (row_shr 1/2/4/8, row_bcast:15 rows{1,3}, row_bcast:31 rows{2,3});
// invalid/masked lanes return old = 1.0f = multiplicative identity.
#define DPP_MUL(x, ctrl, rmask)                                               \
  x *= __int_as_float(__builtin_amdgcn_update_dpp(                            \
      0x3f800000, __float_as_int(x), ctrl, rmask, 0xF, false))

__global__ __launch_bounds__(256) void chol_from_z_kernel(
    const float* __restrict__ z, float* __restrict__ out, int nrows_total)
{
    const int gtid = blockIdx.x * blockDim.x + threadIdx.x;
    const int wid  = gtid >> 6;            // one wave per row
    const int lane = threadIdx.x & 63;
    if (wid >= nrows_total) return;

    const int b = wid >> 7;                // batch
    const int i = wid & 127;               // row within batch

    const float* __restrict__ zr = z + (size_t)b * NZ + (size_t)((i * (i - 1)) >> 1);

    const int p0 = lane << 1;              // element 2l
    const int p1 = p0 | 1;                 // element 2l+1

    // Predicated lane-contiguous loads (8B lane stride; 512B span per wave)
    const float zx = (p0 < i) ? zr[p0] : 0.0f;
    const float zy = (p1 < i) ? zr[p1] : 0.0f;

    // Factors f = 1 - z^2 (masked positions give exactly 1.0)
    const float fa   = fmaf(-zx, zx, 1.0f);
    const float fb   = fmaf(-zy, zy, 1.0f);
    const float pair = fa * fb;

    // Inclusive multiplicative scan of pair across 64 lanes (12 VALU insts)
    float x = pair;
    DPP_MUL(x, 0x111, 0xF);   // row_shr:1
    DPP_MUL(x, 0x112, 0xF);   // row_shr:2
    DPP_MUL(x, 0x114, 0xF);   // row_shr:4
    DPP_MUL(x, 0x118, 0xF);   // row_shr:8
    DPP_MUL(x, 0x142, 0xA);   // row_bcast:15 -> rows 1,3
    DPP_MUL(x, 0x143, 0xC);   // row_bcast:31 -> rows 2,3

    // Exclusive prefix: e = x / pair  (pair >= 0.036 for |z|<=0.9; masked = 1)
    const float e    = x * __builtin_amdgcn_rcpf(pair);
    const float pre1 = e * fa;

    const float sq0 = __builtin_amdgcn_sqrtf(fmaxf(e,    EPSF));
    const float sq1 = __builtin_amdgcn_sqrtf(fmaxf(pre1, EPSF));

    const float ox = (p0 == i) ? sq0 : zx * sq0;   // zx=0 for p0>i -> 0
    const float oy = (p1 == i) ? sq1 : zy * sq1;

    // Contiguous 512B store per wave (8B aligned: row*512 + 8*lane)
    *reinterpret_cast<float2*>(out + (size_t)wid * NROW + p0) = make_float2(ox, oy);
}

extern "C" void kernel_launch(void* const* d_in, const int* in_sizes, int n_in,
                              void* d_out, int out_size, void* d_ws, size_t ws_size,
                              hipStream_t stream)
{
    const float* z = (const float*)d_in[0];
    float* out = (float*)d_out;

    const int B = in_sizes[0] / NZ;              // 2048
    const int nrows_total = B * NROW;            // 262144 rows = 262144 waves

    const int block = 256;                       // 4 waves per block
    const long long threads = (long long)nrows_total * 64;
    const int grid = (int)((threads + block - 1) / block);   // 65536 blocks
    chol_from_z_kernel<<<grid, block, 0, stream>>>(z, out, nrows_total);
}

// Round 5
// 39.754 us; speedup vs baseline: 1.7110x; 1.0272x over previous
//
#include <hip/hip_runtime.h>

#define NROW 128
#define NZ   8128      // 128*127/2
#define EPSF 1e-12f

// One WAVE per TWO rows: lanes 0-31 -> row 2w, lanes 32-63 -> row 2w+1.
// Each lane owns 4 contiguous elements [4l, 4l+3] of its row.
// Closed form: 1 - s_j = prod_{k<j} (1 - z_k^2)   (telescoped recurrence)
//   L[i,j] = z[i,j]*sqrt(max(P_j,EPS)) (j<i), L[i,i]=sqrt(max(P_i,EPS)), 0 above.
// 32-lane segmented multiplicative scan via DPP: row_shr 1/2/4/8 (never
// crosses 16-lane rows; invalid lanes yield old = 1.0f identity) then
// row_bcast:15 masked to rows 1,3 (lane15 -> 16..31, lane47 -> 48..63).
#define DPP_MUL(x, ctrl, rmask)                                               \
  x *= __int_as_float(__builtin_amdgcn_update_dpp(                            \
      0x3f800000, __float_as_int(x), ctrl, rmask, 0xF, false))

__global__ __launch_bounds__(256) void chol_from_z_kernel(
    const float* __restrict__ z, float* __restrict__ out)
{
    const int gtid = blockIdx.x * blockDim.x + threadIdx.x;
    const int w    = gtid >> 6;            // wave id: rows 2w, 2w+1
    const int lane = threadIdx.x & 63;
    const int half = lane >> 5;            // 0 or 1
    const int l    = lane & 31;            // lane within 32-half

    const int row = (w << 1) | half;
    const int b   = row >> 7;              // batch
    const int i   = row & 127;             // row within batch

    const float* __restrict__ zr = z + (size_t)b * NZ + (size_t)((i * (i - 1)) >> 1);
    const int base = l << 2;               // first of this lane's 4 elements

    // Predicated loads (mask upper triangle; also avoids past-end read on last row)
    float zt[4];
    #pragma unroll
    for (int t = 0; t < 4; ++t) {
        const int p = base + t;
        zt[t] = (p < i) ? zr[p] : 0.0f;
    }

    // Lane-local inclusive products of factors f = 1 - z^2 (masked -> exactly 1)
    float c0 = fmaf(-zt[0], zt[0], 1.0f);
    float c1 = c0 * fmaf(-zt[1], zt[1], 1.0f);
    float c2 = c1 * fmaf(-zt[2], zt[2], 1.0f);
    float c3 = c2 * fmaf(-zt[3], zt[3], 1.0f);

    // Segmented 32-lane inclusive scan of c3 (10 VALU insts)
    float x = c3;
    DPP_MUL(x, 0x111, 0xF);   // row_shr:1
    DPP_MUL(x, 0x112, 0xF);   // row_shr:2
    DPP_MUL(x, 0x114, 0xF);   // row_shr:4
    DPP_MUL(x, 0x118, 0xF);   // row_shr:8
    DPP_MUL(x, 0x142, 0xA);   // row_bcast:15 -> rows 1,3 only

    // Exclusive prefix for this lane's block: e = x / c3  (c3 >= 1.3e-3 for |z|<=0.9)
    const float e = x * __builtin_amdgcn_rcpf(c3);

    const float pre0 = e;
    const float pre1 = e * c0;
    const float pre2 = e * c1;
    const float pre3 = e * c2;

    const float sq0 = __builtin_amdgcn_sqrtf(fmaxf(pre0, EPSF));
    const float sq1 = __builtin_amdgcn_sqrtf(fmaxf(pre1, EPSF));
    const float sq2 = __builtin_amdgcn_sqrtf(fmaxf(pre2, EPSF));
    const float sq3 = __builtin_amdgcn_sqrtf(fmaxf(pre3, EPSF));

    const float o0 = (base + 0 == i) ? sq0 : zt[0] * sq0;  // zt=0 above diag -> 0
    const float o1 = (base + 1 == i) ? sq1 : zt[1] * sq1;
    const float o2 = (base + 2 == i) ? sq2 : zt[2] * sq2;
    const float o3 = (base + 3 == i) ? sq3 : zt[3] * sq3;

    // Aligned float4 store: rows are 512B-aligned, base is 16B-aligned.
    *reinterpret_cast<float4*>(out + (size_t)row * NROW + base) =
        make_float4(o0, o1, o2, o3);
}

extern "C" void kernel_launch(void* const* d_in, const int* in_sizes, int n_in,
                              void* d_out, int out_size, void* d_ws, size_t ws_size,
                              hipStream_t stream)
{
    const float* z = (const float*)d_in[0];
    float* out = (float*)d_out;

    const int B = in_sizes[0] / NZ;              // 2048
    const int nrows_total = B * NROW;            // 262144 rows
    const int nwaves = nrows_total >> 1;         // 131072 waves (2 rows each)

    const int block = 256;                       // 4 waves per block
    const int grid = (nwaves * 64) / block;      // 32768 blocks, exact cover
    chol_from_z_kernel<<<grid, block, 0, stream>>>(z, out);
}

// Round 6
// 37.999 us; speedup vs baseline: 1.7900x; 1.0462x over previous
//
#include <hip/hip_runtime.h>

#define NROW 128
#define NZ   8128      // 128*127/2
#define EPSF 1e-12f

// One WAVE per TWO rows: lanes 0-31 -> row 2w, lanes 32-63 -> row 2w+1.
// INTERLEAVED map: lane l (within its 32-half) owns positions {l, 32+l, 64+l, 96+l},
// so every global load/store instruction is lane-contiguous (128B per half,
// ~5 cachelines/inst instead of ~17 for the blocked map).
//
// Closed form: 1 - s_j = prod_{k<j}(1 - z_k^2)  (telescoped scan recurrence)
//   L[i,j] = z[i,j]*sqrt(max(P_j,EPS)) (j<i), L[i,i]=sqrt(max(P_i,EPS)), 0 above.
// P for position p = q*32+l:  P = R_q * g_q(l) / f_q(l), where
//   f_q = per-lane factor, g_q = 32-lane segmented inclusive scan (5 DPP muls),
//   R_q = product of totals of chunks < q (per-half ds_swizzle broadcast of lane31).
#define DPP_MUL(x, ctrl, rmask)                                               \
  x *= __int_as_float(__builtin_amdgcn_update_dpp(                            \
      0x3f800000, __float_as_int(x), ctrl, rmask, 0xF, false))

__global__ __launch_bounds__(256) void chol_from_z_kernel(
    const float* __restrict__ z, float* __restrict__ out)
{
    const int gtid = blockIdx.x * blockDim.x + threadIdx.x;
    const int w    = gtid >> 6;            // wave id: rows 2w, 2w+1
    const int lane = threadIdx.x & 63;
    const int half = lane >> 5;            // 0 or 1
    const int l    = lane & 31;            // lane within 32-half

    const int row = (w << 1) | half;
    const int b   = row >> 7;              // batch
    const int i   = row & 127;             // row within batch

    const float* __restrict__ zr = z + (size_t)b * NZ + (size_t)((i * (i - 1)) >> 1);

    // Loads: chunk q reads positions q*32 + l  (contiguous 128B per half).
    // Predicated (masks upper triangle; avoids 4B past-end read on last row).
    float zq[4], f[4], r[4];
    #pragma unroll
    for (int q = 0; q < 4; ++q) {
        const int p = (q << 5) + l;
        zq[q] = (p < i) ? zr[p] : 0.0f;
        f[q]  = fmaf(-zq[q], zq[q], 1.0f);          // masked -> exactly 1.0
        r[q]  = __builtin_amdgcn_rcpf(f[q]);        // early, overlaps the scans
    }

    // 4 independent 32-lane segmented inclusive multiplicative scans (DPP)
    float g[4];
    #pragma unroll
    for (int q = 0; q < 4; ++q) {
        float x = f[q];
        DPP_MUL(x, 0x111, 0xF);   // row_shr:1
        DPP_MUL(x, 0x112, 0xF);   // row_shr:2
        DPP_MUL(x, 0x114, 0xF);   // row_shr:4
        DPP_MUL(x, 0x118, 0xF);   // row_shr:8
        DPP_MUL(x, 0x142, 0xA);   // row_bcast:15 -> rows 1,3 only
        g[q] = x;
    }

    // Chunk totals: broadcast lane31 of each 32-half (ds_swizzle BitMode and=0,or=31)
    const float t0 = __int_as_float(__builtin_amdgcn_ds_swizzle(__float_as_int(g[0]), 0x3E0));
    const float t1 = __int_as_float(__builtin_amdgcn_ds_swizzle(__float_as_int(g[1]), 0x3E0));
    const float t2 = __int_as_float(__builtin_amdgcn_ds_swizzle(__float_as_int(g[2]), 0x3E0));

    const float R1 = t0;
    const float R2 = t0 * t1;
    const float R3 = R2 * t2;

    // Exclusive prefixes per position: pre = R_q * g_q / f_q
    const float pre0 =      g[0] * r[0];
    const float pre1 = R1 * (g[1] * r[1]);
    const float pre2 = R2 * (g[2] * r[2]);
    const float pre3 = R3 * (g[3] * r[3]);

    const float sq0 = __builtin_amdgcn_sqrtf(fmaxf(pre0, EPSF));
    const float sq1 = __builtin_amdgcn_sqrtf(fmaxf(pre1, EPSF));
    const float sq2 = __builtin_amdgcn_sqrtf(fmaxf(pre2, EPSF));
    const float sq3 = __builtin_amdgcn_sqrtf(fmaxf(pre3, EPSF));

    const int p0 = l, p1 = 32 + l, p2 = 64 + l, p3 = 96 + l;
    const float o0 = (p0 == i) ? sq0 : zq[0] * sq0;   // zq=0 above diag -> 0
    const float o1 = (p1 == i) ? sq1 : zq[1] * sq1;
    const float o2 = (p2 == i) ? sq2 : zq[2] * sq2;
    const float o3 = (p3 == i) ? sq3 : zq[3] * sq3;

    // Stores: chunk q writes positions q*32+l (contiguous 128B per half, full lines)
    float* __restrict__ orow = out + (size_t)row * NROW + l;
    orow[0]  = o0;
    orow[32] = o1;
    orow[64] = o2;
    orow[96] = o3;
}

extern "C" void kernel_launch(void* const* d_in, const int* in_sizes, int n_in,
                              void* d_out, int out_size, void* d_ws, size_t ws_size,
                              hipStream_t stream)
{
    const float* z = (const float*)d_in[0];
    float* out = (float*)d_out;

    const int B = in_sizes[0] / NZ;              // 2048
    const int nrows_total = B * NROW;            // 262144 rows
    const int nwaves = nrows_total >> 1;         // 131072 waves (2 rows each)

    const int block = 256;                       // 4 waves per block
    const int grid = (nwaves * 64) / block;      // 32768 blocks, exact cover
    chol_from_z_kernel<<<grid, block, 0, stream>>>(z, out);
}

// Round 7
// 37.176 us; speedup vs baseline: 1.8297x; 1.0221x over previous
//
#include <hip/hip_runtime.h>

#define NROW 128
#define NZ   8128      // 128*127/2
#define EPSF 1e-12f
#define RPW  8         // rows per wave (8 | 128 -> one batch per wave)

// One WAVE per 8 consecutive rows. Per row, lane l owns elements {2l, 2l+1}
// (aligned float2 store, 512B contiguous per row).
// Closed form: 1 - s_j = prod_{k<j}(1 - z_k^2)  (telescoped scan recurrence)
//   L[i,j] = z[i,j]*sqrt(max(P_j,EPS)) (j<i), L[i,i]=sqrt(max(P_i,EPS)), 0 above.
// Full 64-lane multiplicative scan in 6 DPP muls (validated in R4):
//   row_shr 1/2/4/8, row_bcast:15 -> rows{1,3}, row_bcast:31 -> rows{2,3};
//   invalid lanes return old = 1.0f = multiplicative identity.
// Loads are UNpredicated with in-batch clamped addresses (min with NZ-1):
// for live lanes (p<i) the clamp is a no-op (base+i-1 <= 8127); dead lanes
// read in-bounds garbage that is masked out via cndmask on f / o.
#define DPP_MUL(x, ctrl, rmask)                                               \
  x *= __int_as_float(__builtin_amdgcn_update_dpp(                            \
      0x3f800000, __float_as_int(x), ctrl, rmask, 0xF, false))

__global__ __launch_bounds__(256) void chol_from_z_kernel(
    const float* __restrict__ z, float* __restrict__ out)
{
    const int gtid = blockIdx.x * blockDim.x + threadIdx.x;
    const int w    = gtid >> 6;            // wave id
    const int lane = threadIdx.x & 63;

    const int row0 = w * RPW;              // 8 consecutive rows, same batch
    const int b    = row0 >> 7;
    const float* __restrict__ zb = z + (size_t)b * NZ;

    const int p0 = lane << 1;              // element 2l
    const int p1 = p0 | 1;                 // element 2l+1

    // ---- Phase 1: issue all 16 loads (no exec masking, addresses clamped) ----
    float zA[RPW], zB[RPW];
    #pragma unroll
    for (int k = 0; k < RPW; ++k) {
        const int i    = (row0 + k) & 127;
        const int base = (i * (i - 1)) >> 1;
        const int a0   = min(base + p0, NZ - 1);   // never alters live lanes
        const int a1   = min(base + p1, NZ - 1);
        zA[k] = zb[a0];
        zB[k] = zb[a1];
    }

    // ---- Phase 2: 8 independent scan+store streams ----
    #pragma unroll
    for (int k = 0; k < RPW; ++k) {
        const int  i  = (row0 + k) & 127;
        const bool m0 = (p0 < i);
        const bool m1 = (p1 < i);
        const float z0 = zA[k], z1 = zB[k];

        const float f0   = m0 ? fmaf(-z0, z0, 1.0f) : 1.0f;
        const float f1   = m1 ? fmaf(-z1, z1, 1.0f) : 1.0f;
        const float pair = f0 * f1;

        // Inclusive 64-lane multiplicative scan of pair (6 DPP muls)
        float x = pair;
        DPP_MUL(x, 0x111, 0xF);   // row_shr:1
        DPP_MUL(x, 0x112, 0xF);   // row_shr:2
        DPP_MUL(x, 0x114, 0xF);   // row_shr:4
        DPP_MUL(x, 0x118, 0xF);   // row_shr:8
        DPP_MUL(x, 0x142, 0xA);   // row_bcast:15 -> rows 1,3
        DPP_MUL(x, 0x143, 0xC);   // row_bcast:31 -> rows 2,3

        // Exclusive prefix: e = x / pair (pair >= 0.036 for |z|<=0.9; masked = 1)
        const float e    = x * __builtin_amdgcn_rcpf(pair);
        const float pre1 = e * f0;

        const float sq0 = __builtin_amdgcn_sqrtf(fmaxf(e,    EPSF));
        const float sq1 = __builtin_amdgcn_sqrtf(fmaxf(pre1, EPSF));

        const float o0 = m0 ? z0 * sq0 : ((p0 == i) ? sq0 : 0.0f);
        const float o1 = m1 ? z1 * sq1 : ((p1 == i) ? sq1 : 0.0f);

        // Aligned float2 store: row base 512B-aligned, offset 8B-aligned.
        *reinterpret_cast<float2*>(out + (size_t)(row0 + k) * NROW + p0) =
            make_float2(o0, o1);
    }
}

extern "C" void kernel_launch(void* const* d_in, const int* in_sizes, int n_in,
                              void* d_out, int out_size, void* d_ws, size_t ws_size,
                              hipStream_t stream)
{
    const float* z = (const float*)d_in[0];
    float* out = (float*)d_out;

    const int B = in_sizes[0] / NZ;              // 2048
    const int nrows_total = B * NROW;            // 262144 rows
    const int nwaves = nrows_total / RPW;        // 32768 waves

    const int block = 256;                       // 4 waves per block
    const int grid = (nwaves * 64) / block;      // 8192 blocks, exact cover
    chol_from_z_kernel<<<grid, block, 0, stream>>>(z, out);
}